// Round 11
// baseline (5661.391 us; speedup 1.0000x reference)
//
#include <hip/hip_runtime.h>
#include <hip/hip_bf16.h>
#include <hip/hip_fp16.h>

#define N_NODES 20000
#define E_EDGES 320000
#define CIN 128
#define HDIM 128
#define EDGE_DIM 16
#define SDIM 3
#define KS 3
#define KK 27           // 3^3 kernel weight matrices
#define NB 28           // 27 spline blocks + 1 root-weight block
#define S_TAPS 8
#define MLP_HID 6
#define TN 16           // dst nodes per workgroup (one MFMA m-tile)
#define TC 32           // channels per pass (4 passes cover CIN=128)
#define TSTRIDE (NB * TC + 4)   // 900 floats; +4 pad breaks 16-way LDS bank aliasing

typedef __attribute__((ext_vector_type(8))) short v8s;   // 8 bf16 (4 VGPRs)
typedef __attribute__((ext_vector_type(4))) float v4f;   // MFMA accumulator
typedef unsigned short ush;
typedef unsigned char uch;

static __device__ __forceinline__ short f2bf(float v) {
    unsigned u = __float_as_uint(v);
    unsigned r = (u + 0x7fffu + ((u >> 16) & 1u)) >> 16;   // RTNE
    return (short)r;
}
static __device__ __forceinline__ float bf2f(unsigned s) {
    return __uint_as_float((s & 0xffffu) << 16);
}
static __device__ __forceinline__ unsigned short f2h(float f) {
    __half h = __float2half(f);
    return __half_as_ushort(h);
}
static __device__ __forceinline__ float h2f(unsigned u) {
    __half_raw r; r.x = (unsigned short)u;
    return __half2float(__half(r));
}

// ---------------------------------------------------------------------------
// edge_index dtype detect + decode (int64 vs int32 storage)
// ---------------------------------------------------------------------------
__global__ void detect_kernel(const unsigned int* __restrict__ e, int* __restrict__ flag) {
    __shared__ int s_nz;
    if (threadIdx.x == 0) s_nz = 0;
    __syncthreads();
    unsigned int v = e[threadIdx.x * 2 + 1];
    if (v != 0) atomicAdd(&s_nz, 1);
    __syncthreads();
    if (threadIdx.x == 0) *flag = (s_nz > 0) ? 1 : 0;
}

__global__ void decode_edges(const void* __restrict__ eraw, const int* __restrict__ flag,
                             int* __restrict__ e32, int n) {
    int i = blockIdx.x * blockDim.x + threadIdx.x;
    if (i >= n) return;
    if (*flag) e32[i] = ((const int*)eraw)[i];
    else       e32[i] = (int)(((const long long*)eraw)[i]);
}

// ---------------------------------------------------------------------------
// Edge MLP (16->6 relu ->3 sigmoid) + degree-1 open B-spline basis.
// Emits fp16 weights (wq[E][8]) and byte kernel indices (kq[E][8]).
// ---------------------------------------------------------------------------
__global__ void edge_basis(const float* __restrict__ ea,
                           const float* __restrict__ Wp1, const float* __restrict__ bp1,
                           const float* __restrict__ Wp2, const float* __restrict__ bp2,
                           ush* __restrict__ wq, uch* __restrict__ kq) {
    __shared__ float sW1[EDGE_DIM * MLP_HID];
    __shared__ float sb1[MLP_HID];
    __shared__ float sW2[MLP_HID * SDIM];
    __shared__ float sb2[SDIM];
    int t = threadIdx.x;
    if (t < EDGE_DIM * MLP_HID) sW1[t] = Wp1[t];
    if (t < MLP_HID)            sb1[t] = bp1[t];
    if (t < MLP_HID * SDIM)     sW2[t] = Wp2[t];
    if (t < SDIM)               sb2[t] = bp2[t];
    __syncthreads();
    int e = blockIdx.x * blockDim.x + t;
    if (e >= E_EDGES) return;

    float a[EDGE_DIM];
#pragma unroll
    for (int i = 0; i < EDGE_DIM; i++) a[i] = ea[(long)e * EDGE_DIM + i];

    float hid[MLP_HID];
#pragma unroll
    for (int j = 0; j < MLP_HID; j++) {
        float s = sb1[j];
#pragma unroll
        for (int i = 0; i < EDGE_DIM; i++) s += a[i] * sW1[i * MLP_HID + j];
        hid[j] = fmaxf(s, 0.f);
    }

    float lo[SDIM], fr[SDIM];
#pragma unroll
    for (int d = 0; d < SDIM; d++) {
        float s = sb2[d];
#pragma unroll
        for (int j = 0; j < MLP_HID; j++) s += hid[j] * sW2[j * SDIM + d];
        float u = 1.f / (1.f + expf(-s));
        float v = u * (float)(KS - 1);
        float l = floorf(v);
        l = fminf(fmaxf(l, 0.f), (float)(KS - 2));
        lo[d] = l;
        fr[d] = v - l;
    }

#pragma unroll
    for (int s = 0; s < S_TAPS; s++) {
        float w = 1.f;
        int idx = 0, stride = 1;
#pragma unroll
        for (int d = 0; d < SDIM; d++) {
            int bit = (s >> d) & 1;
            w *= bit ? fr[d] : (1.f - fr[d]);
            idx += ((int)lo[d] + bit) * stride;
            stride *= KS;
        }
        wq[(long)e * S_TAPS + s] = f2h(w);
        kq[(long)e * S_TAPS + s] = (uch)idx;
    }
}

// ---------------------------------------------------------------------------
// CSR build (per dst node) — built once, reused for 3 layers
// ---------------------------------------------------------------------------
__global__ void zero_int(int* __restrict__ p, int n) {
    int i = blockIdx.x * blockDim.x + threadIdx.x;
    if (i < n) p[i] = 0;
}

__global__ void hist_kernel(const int* __restrict__ dst, int* __restrict__ hist) {
    int e = blockIdx.x * blockDim.x + threadIdx.x;
    if (e < E_EDGES) atomicAdd(&hist[dst[e]], 1);
}

__global__ void scan_kernel(const int* __restrict__ hist, int* __restrict__ rowptr) {
    __shared__ int part[1024];
    int t = threadIdx.x;
    const int per = (N_NODES + 1023) / 1024;   // 20
    int base = t * per;
    int s = 0;
    for (int i = 0; i < per; i++) {
        int idx = base + i;
        if (idx < N_NODES) s += hist[idx];
    }
    part[t] = s;
    __syncthreads();
    for (int off = 1; off < 1024; off <<= 1) {
        int v = (t >= off) ? part[t - off] : 0;
        __syncthreads();
        part[t] += v;
        __syncthreads();
    }
    int run = (t == 0) ? 0 : part[t - 1];
    for (int i = 0; i < per; i++) {
        int idx = base + i;
        if (idx < N_NODES) { rowptr[idx] = run; run += hist[idx]; }
    }
    if (t == 1023) rowptr[N_NODES] = run;
}

__global__ void perm_kernel(const int* __restrict__ dst, const int* __restrict__ rowptr,
                            int* __restrict__ cursor, int* __restrict__ eperm) {
    int e = blockIdx.x * blockDim.x + threadIdx.x;
    if (e >= E_EDGES) return;
    int d = dst[e];
    int pos = rowptr[d] + atomicAdd(&cursor[d], 1);
    eperm[pos] = e;
}

// Pack metadata into CSR order: sequential streaming in the fused kernel.
// dstp = dst & 15 (node-local index within its 16-node group).
__global__ void pack_csr(const int* __restrict__ eperm, const int* __restrict__ src,
                         const int* __restrict__ dst,
                         const ush* __restrict__ wq, const uch* __restrict__ kq,
                         int* __restrict__ srcp, ush* __restrict__ wp,
                         uch* __restrict__ kp, uch* __restrict__ dstp) {
    int j = blockIdx.x * blockDim.x + threadIdx.x;
    if (j >= E_EDGES) return;
    int e = eperm[j];
    srcp[j] = src[e];
    dstp[j] = (uch)(dst[e] & (TN - 1));
    *(uint4*)(wp + (size_t)j * 8) = *(const uint4*)(wq + (size_t)e * 8);
    *(uint2*)(kp + (size_t)j * 8) = *(const uint2*)(kq + (size_t)e * 8);
}

// ---------------------------------------------------------------------------
// Convert activations -> bf16 row-major (with relu for layers > 0).
// ---------------------------------------------------------------------------
__global__ void convX_kernel(const float* __restrict__ A, ush* __restrict__ xb,
                             int do_relu) {
    int i = blockIdx.x * blockDim.x + threadIdx.x;
    if (i >= N_NODES * CIN) return;
    float v = A[i];
    if (do_relu) v = fmaxf(v, 0.f);
    xb[i] = (ush)f2bf(v);
}

// ---------------------------------------------------------------------------
// Pack [W (27 blocks) | Wr] -> bf16 in MFMA B-fragment layout.
// Wh[kb][ks4][nt][lane][8]; element = B[cin = ks4*32+(lane>>4)*8+j][o = nt*16+(lane&15)]
// ---------------------------------------------------------------------------
__global__ void packW_kernel(const float* __restrict__ W, const float* __restrict__ Wr,
                             short* __restrict__ hi) {
    int gid = blockIdx.x * blockDim.x + threadIdx.x;
    if (gid >= NB * 4 * 8 * 64) return;
    int lane = gid & 63;
    int nt = (gid >> 6) & 7;
    int ks = (gid >> 9) & 3;
    int kb = gid >> 11;
    int i0 = ks * 32 + ((lane >> 4) & 3) * 8;
    int o = nt * 16 + (lane & 15);
    const float* src = (kb < KK) ? (W + (long)kb * 16384 + (long)i0 * 128 + o)
                                 : (Wr + (long)i0 * 128 + o);
    long off = ((long)((kb * 4 + ks) * 8 + nt) * 64 + lane) * 8;
#pragma unroll
    for (int j = 0; j < 8; j++) {
        float v = src[(long)j * 128];
        hi[off + j] = f2bf(v);
    }
}

// ---------------------------------------------------------------------------
// Fused SplineConv layer pass: one WG = 16 dst nodes x 32 channels (pass-th
// quarter of CIN). Stage A: accumulate T[node][k][ch] in LDS via ds_add_f32
// over the node group's CSR edge range (no global scatter, no Z array).
// Stage B: MFMA T x Wh -> out[16 x 128] partial; pass 0 writes (+bias),
// passes 1..3 RMW-add (sequential launches -> race-free).
// ---------------------------------------------------------------------------
__global__ __launch_bounds__(256) void fused_kernel(
    const ush* __restrict__ xb, const int* __restrict__ rowptr,
    const int* __restrict__ srcp, const ush* __restrict__ wp,
    const uch* __restrict__ kp, const uch* __restrict__ dstp,
    const short* __restrict__ Wh, const float* __restrict__ bias,
    float* __restrict__ outp, int pass)
{
    __shared__ float T[TN * TSTRIDE];   // 16*900*4 = 57600 B

    int tid = threadIdx.x;
    int n0 = blockIdx.x * TN;

    // zero the whole tile (root bin overwritten below after the barrier)
    for (int i = tid; i < TN * TSTRIDE; i += 256) T[i] = 0.f;
    __syncthreads();

    // root-weight bin 27: T[node][27][ch] = x[n0+node][pass*32+ch]
    for (int i = tid; i < TN * TC; i += 256) {
        int node = i >> 5, ch = i & (TC - 1);
        T[node * TSTRIDE + KK * TC + ch] =
            bf2f(xb[(size_t)(n0 + node) * CIN + pass * TC + ch]);
    }

    // Stage A: edge accumulation. slot = which of 8 half-waves; 32 ch lanes.
    int wave = tid >> 6;
    int half = (tid >> 5) & 1;
    int ch = tid & (TC - 1);
    int slot = wave * 2 + half;
    int jb = rowptr[n0], je = rowptr[n0 + TN];

#pragma unroll 2
    for (int j = jb + slot; j < je; j += 8) {
        int src = srcp[j];
        int node = dstp[j];
        float xv = bf2f(xb[(size_t)src * CIN + pass * TC + ch]);
        uint4 wb = *(const uint4*)(wp + (size_t)j * 8);
        uint2 kb = *(const uint2*)(kp + (size_t)j * 8);
        float* tb = &T[node * TSTRIDE + ch];
        atomicAdd(tb + (kb.x & 0xff) * TC,         h2f(wb.x & 0xffff) * xv);
        atomicAdd(tb + ((kb.x >> 8) & 0xff) * TC,  h2f(wb.x >> 16) * xv);
        atomicAdd(tb + ((kb.x >> 16) & 0xff) * TC, h2f(wb.y & 0xffff) * xv);
        atomicAdd(tb + (kb.x >> 24) * TC,          h2f(wb.y >> 16) * xv);
        atomicAdd(tb + (kb.y & 0xff) * TC,         h2f(wb.z & 0xffff) * xv);
        atomicAdd(tb + ((kb.y >> 8) & 0xff) * TC,  h2f(wb.z >> 16) * xv);
        atomicAdd(tb + ((kb.y >> 16) & 0xff) * TC, h2f(wb.w & 0xffff) * xv);
        atomicAdd(tb + (kb.y >> 24) * TC,          h2f(wb.w >> 16) * xv);
    }
    __syncthreads();

    // Stage B: MFMA. K = 28 bins x 32 ch = 28 ksteps of 32.
    int lane = tid & 63;
    int row = lane & 15;
    int ch0 = ((lane >> 4) & 3) * 8;
    v4f acc0 = (v4f){0.f, 0.f, 0.f, 0.f};
    v4f acc1 = (v4f){0.f, 0.f, 0.f, 0.f};
    int nt0 = wave * 2, nt1 = wave * 2 + 1;

#pragma unroll
    for (int kb = 0; kb < NB; kb++) {
        const float* tp = &T[row * TSTRIDE + kb * TC + ch0];
        v8s a;
#pragma unroll
        for (int q = 0; q < 8; q++) a[q] = f2bf(tp[q]);
        long b0 = ((long)((kb * 4 + pass) * 8 + nt0) * 64 + lane) * 8;
        long b1 = ((long)((kb * 4 + pass) * 8 + nt1) * 64 + lane) * 8;
        v8s bh0 = *(const v8s*)(Wh + b0);
        v8s bh1 = *(const v8s*)(Wh + b1);
        acc0 = __builtin_amdgcn_mfma_f32_16x16x32_bf16(a, bh0, acc0, 0, 0, 0);
        acc1 = __builtin_amdgcn_mfma_f32_16x16x32_bf16(a, bh1, acc1, 0, 0, 0);
    }

    // Epilogue. C/D layout: col = lane&15, row-in-tile = (lane>>4)*4 + r.
    int colr = lane & 15;
    int rbase = ((lane >> 4) & 3) * 4;
#pragma unroll
    for (int r = 0; r < 4; r++) {
        int n = n0 + rbase + r;
        size_t o0 = (size_t)n * HDIM + nt0 * 16 + colr;
        size_t o1 = (size_t)n * HDIM + nt1 * 16 + colr;
        if (pass == 0) {
            outp[o0] = acc0[r] + bias[nt0 * 16 + colr];
            outp[o1] = acc1[r] + bias[nt1 * 16 + colr];
        } else {
            outp[o0] += acc0[r];
            outp[o1] += acc1[r];
        }
    }
}

// ---------------------------------------------------------------------------
extern "C" void kernel_launch(void* const* d_in, const int* in_sizes, int n_in,
                              void* d_out, int out_size, void* d_ws, size_t ws_size,
                              hipStream_t stream) {
    const float* x   = (const float*)d_in[0];
    const void*  eix = d_in[1];
    const float* ea  = (const float*)d_in[2];
    const float* Wp1 = (const float*)d_in[3];
    const float* bp1 = (const float*)d_in[4];
    const float* Wp2 = (const float*)d_in[5];
    const float* bp2 = (const float*)d_in[6];
    const float* W[3]  = {(const float*)d_in[7],  (const float*)d_in[10], (const float*)d_in[13]};
    const float* Wr[3] = {(const float*)d_in[8],  (const float*)d_in[11], (const float*)d_in[14]};
    const float* b[3]  = {(const float*)d_in[9],  (const float*)d_in[12], (const float*)d_in[15]};
    float* out = (float*)d_out;

    char* ws = (char*)d_ws;
    size_t off = 0;
    auto walloc = [&](size_t bytes) -> void* {
        void* p = ws + off;
        off = (off + bytes + 255) & ~(size_t)255;
        return p;
    };
    int*   flag   = (int*)  walloc(sizeof(int));
    int*   e32    = (int*)  walloc(sizeof(int) * 2 * E_EDGES);
    ush*   wq     = (ush*)  walloc(sizeof(ush) * (size_t)E_EDGES * 8);
    uch*   kq     = (uch*)  walloc((size_t)E_EDGES * 8);
    float* h0     = (float*)walloc(sizeof(float) * (size_t)N_NODES * HDIM);
    float* h1     = (float*)walloc(sizeof(float) * (size_t)N_NODES * HDIM);
    ush*   xb     = (ush*)  walloc(sizeof(ush) * (size_t)N_NODES * CIN);
    short* Wh     = (short*)walloc(sizeof(short) * (size_t)NB * 128 * 128);
    int*   eperm  = (int*)  walloc(sizeof(int) * E_EDGES);
    int*   srcp   = (int*)  walloc(sizeof(int) * E_EDGES);
    ush*   wp     = (ush*)  walloc(sizeof(ush) * (size_t)E_EDGES * 8);
    uch*   kp     = (uch*)  walloc((size_t)E_EDGES * 8);
    uch*   dstp   = (uch*)  walloc((size_t)E_EDGES);
    int*   hist   = (int*)  walloc(sizeof(int) * N_NODES);
    int*   cursor = (int*)  walloc(sizeof(int) * N_NODES);
    int*   rowptr = (int*)  walloc(sizeof(int) * (N_NODES + 1));

    int* srcv = e32;
    int* dstv = e32 + E_EDGES;

    detect_kernel<<<1, 1024, 0, stream>>>((const unsigned int*)eix, flag);
    decode_edges<<<(2 * E_EDGES + 255) / 256, 256, 0, stream>>>(eix, flag, e32, 2 * E_EDGES);
    edge_basis<<<(E_EDGES + 255) / 256, 256, 0, stream>>>(ea, Wp1, bp1, Wp2, bp2, wq, kq);

    // CSR by dst node; built once, reused across 3 layers
    zero_int<<<(N_NODES + 255) / 256, 256, 0, stream>>>(hist, N_NODES);
    zero_int<<<(N_NODES + 255) / 256, 256, 0, stream>>>(cursor, N_NODES);
    hist_kernel<<<(E_EDGES + 255) / 256, 256, 0, stream>>>(dstv, hist);
    scan_kernel<<<1, 1024, 0, stream>>>(hist, rowptr);
    perm_kernel<<<(E_EDGES + 255) / 256, 256, 0, stream>>>(dstv, rowptr, cursor, eperm);
    pack_csr<<<(E_EDGES + 255) / 256, 256, 0, stream>>>(eperm, srcv, dstv, wq, kq,
                                                        srcp, wp, kp, dstp);

    const float* lin[3]  = {x, h0, h1};
    float*       lout[3] = {h0, h1, out};

    for (int l = 0; l < 3; l++) {
        convX_kernel<<<(N_NODES * CIN + 255) / 256, 256, 0, stream>>>(
            lin[l], xb, (l > 0) ? 1 : 0);
        packW_kernel<<<(NB * 4 * 8 * 64 + 255) / 256, 256, 0, stream>>>(
            W[l], Wr[l], Wh);
        for (int p = 0; p < 4; p++) {
            fused_kernel<<<N_NODES / TN, 256, 0, stream>>>(
                xb, rowptr, srcp, wp, kp, dstp, Wh, b[l], lout[l], p);
        }
    }
}

// Round 12
// 4046.891 us; speedup vs baseline: 1.3989x; 1.3989x over previous
//
#include <hip/hip_runtime.h>
#include <hip/hip_bf16.h>
#include <hip/hip_fp16.h>

#define N_NODES 20000
#define E_EDGES 320000
#define CIN 128
#define HDIM 128
#define EDGE_DIM 16
#define SDIM 3
#define KS 3
#define KK 27           // 3^3 kernel weight matrices
#define NB 28           // 27 spline blocks + 1 root-weight block
#define S_TAPS 8
#define MLP_HID 6
#define TN 16           // dst nodes per workgroup (one MFMA m-tile)
#define TC 32           // channels per pass (4 passes cover CIN=128)
#define TSTRIDE (NB * TC + 4)    // 900 floats/node; +4 pad de-aliases banks
#define BINS (N_NODES * KK)      // 540000 (dst,k) bins
#define NTAP (E_EDGES * S_TAPS)  // 2,560,000 tap instances

typedef __attribute__((ext_vector_type(8))) short v8s;   // 8 bf16 (4 VGPRs)
typedef __attribute__((ext_vector_type(4))) float v4f;   // MFMA accumulator
typedef unsigned short ush;
typedef unsigned char uch;

static __device__ __forceinline__ short f2bf(float v) {
    unsigned u = __float_as_uint(v);
    unsigned r = (u + 0x7fffu + ((u >> 16) & 1u)) >> 16;   // RTNE
    return (short)r;
}
static __device__ __forceinline__ float bf2f(unsigned s) {
    return __uint_as_float((s & 0xffffu) << 16);
}
static __device__ __forceinline__ unsigned short f2h(float f) {
    __half h = __float2half(f);
    return __half_as_ushort(h);
}
static __device__ __forceinline__ float h2f(unsigned u) {
    __half_raw r; r.x = (unsigned short)u;
    return __half2float(__half(r));
}

// ---------------------------------------------------------------------------
// edge_index dtype detect + decode (int64 vs int32 storage)
// ---------------------------------------------------------------------------
__global__ void detect_kernel(const unsigned int* __restrict__ e, int* __restrict__ flag) {
    __shared__ int s_nz;
    if (threadIdx.x == 0) s_nz = 0;
    __syncthreads();
    unsigned int v = e[threadIdx.x * 2 + 1];
    if (v != 0) atomicAdd(&s_nz, 1);
    __syncthreads();
    if (threadIdx.x == 0) *flag = (s_nz > 0) ? 1 : 0;
}

__global__ void decode_edges(const void* __restrict__ eraw, const int* __restrict__ flag,
                             int* __restrict__ e32, int n) {
    int i = blockIdx.x * blockDim.x + threadIdx.x;
    if (i >= n) return;
    if (*flag) e32[i] = ((const int*)eraw)[i];
    else       e32[i] = (int)(((const long long*)eraw)[i]);
}

// ---------------------------------------------------------------------------
// Edge MLP (16->6 relu ->3 sigmoid) + degree-1 open B-spline basis.
// Emits fp16 weights (wq[E][8]) and byte kernel indices (kq[E][8]).
// ---------------------------------------------------------------------------
__global__ void edge_basis(const float* __restrict__ ea,
                           const float* __restrict__ Wp1, const float* __restrict__ bp1,
                           const float* __restrict__ Wp2, const float* __restrict__ bp2,
                           ush* __restrict__ wq, uch* __restrict__ kq) {
    __shared__ float sW1[EDGE_DIM * MLP_HID];
    __shared__ float sb1[MLP_HID];
    __shared__ float sW2[MLP_HID * SDIM];
    __shared__ float sb2[SDIM];
    int t = threadIdx.x;
    if (t < EDGE_DIM * MLP_HID) sW1[t] = Wp1[t];
    if (t < MLP_HID)            sb1[t] = bp1[t];
    if (t < MLP_HID * SDIM)     sW2[t] = Wp2[t];
    if (t < SDIM)               sb2[t] = bp2[t];
    __syncthreads();
    int e = blockIdx.x * blockDim.x + t;
    if (e >= E_EDGES) return;

    float a[EDGE_DIM];
#pragma unroll
    for (int i = 0; i < EDGE_DIM; i++) a[i] = ea[(long)e * EDGE_DIM + i];

    float hid[MLP_HID];
#pragma unroll
    for (int j = 0; j < MLP_HID; j++) {
        float s = sb1[j];
#pragma unroll
        for (int i = 0; i < EDGE_DIM; i++) s += a[i] * sW1[i * MLP_HID + j];
        hid[j] = fmaxf(s, 0.f);
    }

    float lo[SDIM], fr[SDIM];
#pragma unroll
    for (int d = 0; d < SDIM; d++) {
        float s = sb2[d];
#pragma unroll
        for (int j = 0; j < MLP_HID; j++) s += hid[j] * sW2[j * SDIM + d];
        float u = 1.f / (1.f + expf(-s));
        float v = u * (float)(KS - 1);
        float l = floorf(v);
        l = fminf(fmaxf(l, 0.f), (float)(KS - 2));
        lo[d] = l;
        fr[d] = v - l;
    }

#pragma unroll
    for (int s = 0; s < S_TAPS; s++) {
        float w = 1.f;
        int idx = 0, stride = 1;
#pragma unroll
        for (int d = 0; d < SDIM; d++) {
            int bit = (s >> d) & 1;
            w *= bit ? fr[d] : (1.f - fr[d]);
            idx += ((int)lo[d] + bit) * stride;
            stride *= KS;
        }
        wq[(long)e * S_TAPS + s] = f2h(w);
        kq[(long)e * S_TAPS + s] = (uch)idx;
    }
}

// ---------------------------------------------------------------------------
// Tap-level CSR over (dst,k) bins — built once, reused 3 layers x 4 passes.
// ---------------------------------------------------------------------------
__global__ void zero_int(int* __restrict__ p, int n) {
    int i = blockIdx.x * blockDim.x + threadIdx.x;
    if (i < n) p[i] = 0;
}

__global__ void histT_kernel(const int* __restrict__ dst, const uch* __restrict__ kq,
                             int* __restrict__ hist) {
    int i = blockIdx.x * blockDim.x + threadIdx.x;
    if (i >= NTAP) return;
    atomicAdd(&hist[dst[i >> 3] * KK + kq[i]], 1);
}

// Multi-block exclusive scan: A) per-1024-block local scan + block sum,
// B) scan block sums (1 block), C) add offsets.
__global__ void scanA_kernel(const int* __restrict__ hist, int* __restrict__ rowptr,
                             int* __restrict__ bsum) {
    __shared__ int part[256];
    int t = threadIdx.x;
    int e0 = blockIdx.x * 1024 + t * 4;
    int h[4];
    int s = 0;
#pragma unroll
    for (int i = 0; i < 4; i++) {
        int idx = e0 + i;
        h[i] = (idx < BINS) ? hist[idx] : 0;
        s += h[i];
    }
    part[t] = s;
    __syncthreads();
    for (int off = 1; off < 256; off <<= 1) {
        int v = (t >= off) ? part[t - off] : 0;
        __syncthreads();
        part[t] += v;
        __syncthreads();
    }
    int run = part[t] - s;   // exclusive prefix for this thread
#pragma unroll
    for (int i = 0; i < 4; i++) {
        int idx = e0 + i;
        if (idx < BINS) { rowptr[idx] = run; run += h[i]; }
    }
    if (t == 255) bsum[blockIdx.x] = part[255];
}

__global__ void scanB_kernel(int* __restrict__ bsum, int nblk) {
    __shared__ int part[256];
    int t = threadIdx.x;
    const int per = 4;   // supports up to 1024 blocks
    int base = t * per;
    int v[4];
    int s = 0;
#pragma unroll
    for (int i = 0; i < per; i++) {
        int idx = base + i;
        v[i] = (idx < nblk) ? bsum[idx] : 0;
        s += v[i];
    }
    part[t] = s;
    __syncthreads();
    for (int off = 1; off < 256; off <<= 1) {
        int x = (t >= off) ? part[t - off] : 0;
        __syncthreads();
        part[t] += x;
        __syncthreads();
    }
    int run = part[t] - s;
#pragma unroll
    for (int i = 0; i < per; i++) {
        int idx = base + i;
        if (idx < nblk) { bsum[idx] = run; run += v[i]; }
    }
}

__global__ void scanC_kernel(int* __restrict__ rowptr, const int* __restrict__ bsum) {
    int i = blockIdx.x * blockDim.x + threadIdx.x;
    if (i < BINS) rowptr[i] += bsum[i >> 10];
    if (i == 0) rowptr[BINS] = NTAP;
}

// Scatter tap entries into CSR order (SoA: srcT int, wT fp16).
__global__ void permT_kernel(const int* __restrict__ dst, const int* __restrict__ src,
                             const uch* __restrict__ kq, const ush* __restrict__ wq,
                             const int* __restrict__ rowptr, int* __restrict__ cursor,
                             int* __restrict__ srcT, ush* __restrict__ wT) {
    int i = blockIdx.x * blockDim.x + threadIdx.x;
    if (i >= NTAP) return;
    int e = i >> 3;
    int bin = dst[e] * KK + kq[i];
    int pos = rowptr[bin] + atomicAdd(&cursor[bin], 1);
    srcT[pos] = src[e];
    wT[pos] = wq[i];
}

// ---------------------------------------------------------------------------
// Convert activations -> bf16 row-major (relu for layers > 0).
// ---------------------------------------------------------------------------
__global__ void convX_kernel(const float* __restrict__ A, ush* __restrict__ xb,
                             int do_relu) {
    int i = blockIdx.x * blockDim.x + threadIdx.x;
    if (i >= N_NODES * CIN) return;
    float v = A[i];
    if (do_relu) v = fmaxf(v, 0.f);
    xb[i] = (ush)f2bf(v);
}

// ---------------------------------------------------------------------------
// Pack [W (27 blocks) | Wr] -> bf16 in MFMA B-fragment layout.
// Wh[kb][ks][nt][lane][8]; element = B[cin=ks*32+(lane>>4)*8+j][o=nt*16+(lane&15)]
// ---------------------------------------------------------------------------
__global__ void packW_kernel(const float* __restrict__ W, const float* __restrict__ Wr,
                             short* __restrict__ hi) {
    int gid = blockIdx.x * blockDim.x + threadIdx.x;
    if (gid >= NB * 4 * 8 * 64) return;
    int lane = gid & 63;
    int nt = (gid >> 6) & 7;
    int ks = (gid >> 9) & 3;
    int kb = gid >> 11;
    int i0 = ks * 32 + ((lane >> 4) & 3) * 8;
    int o = nt * 16 + (lane & 15);
    const float* src = (kb < KK) ? (W + (long)kb * 16384 + (long)i0 * 128 + o)
                                 : (Wr + (long)i0 * 128 + o);
    long off = ((long)((kb * 4 + ks) * 8 + nt) * 64 + lane) * 8;
#pragma unroll
    for (int j = 0; j < 8; j++) {
        float v = src[(long)j * 128];
        hi[off + j] = f2bf(v);
    }
}

// ---------------------------------------------------------------------------
// Fused SplineConv pass v2: one WG = 16 dst nodes x 32 channels.
// Stage A: per (node,k) bin, REGISTER-reduce its tap-CSR entry list
// (64 lanes = 32 ch x 2 entry slots), single plain LDS store per bin —
// no atomics, no LDS RMW (each bin owned by exactly one wave).
// Stage B: MFMA T x Wh (verified in R11); pass 0 writes out+bias, else RMW.
// ---------------------------------------------------------------------------
__global__ __launch_bounds__(256) void fused_kernel(
    const ush* __restrict__ xb, const int* __restrict__ rowptrT,
    const int* __restrict__ srcT, const ush* __restrict__ wT,
    const short* __restrict__ Wh, const float* __restrict__ bias,
    float* __restrict__ outp, int pass)
{
    __shared__ float T[TN * TSTRIDE];   // 57600 B

    int tid = threadIdx.x;
    int n0 = blockIdx.x * TN;
    int wave = tid >> 6;
    int lane = tid & 63;
    int ch = lane & (TC - 1);
    int half = lane >> 5;

    // zero-fill T (covers empty bins)
    for (int i = tid; i < TN * TSTRIDE; i += 256) T[i] = 0.f;
    __syncthreads();

    // root bin (k=27): T[node][27][ch] = x[n0+node][pass*32+ch]
    for (int i = tid; i < TN * TC; i += 256) {
        int node = i >> 5;
        T[node * TSTRIDE + KK * TC + (i & (TC - 1))] =
            bf2f(xb[(size_t)(n0 + node) * CIN + pass * TC + (i & (TC - 1))]);
    }

    // Stage A: register-reduce each owned (node,k) bin, one LDS store per bin.
    for (int bi = wave; bi < TN * KK; bi += 4) {
        int node = bi / KK;
        int k = bi - node * KK;
        int bin = (n0 + node) * KK + k;
        int jb = rowptrT[bin], je = rowptrT[bin + 1];
        float acc = 0.f;
        for (int j = jb + half; j < je; j += 2) {
            int s = srcT[j];
            float w = h2f(wT[j]);
            acc += w * bf2f(xb[(size_t)s * CIN + pass * TC + ch]);
        }
        acc += __shfl_xor(acc, 32, 64);
        if (half == 0) T[node * TSTRIDE + k * TC + ch] = acc;
    }
    __syncthreads();

    // Stage B: MFMA. 28 k-steps of 32 over the bins (R11-verified).
    int row = lane & 15;
    int ch0 = ((lane >> 4) & 3) * 8;
    v4f acc0 = (v4f){0.f, 0.f, 0.f, 0.f};
    v4f acc1 = (v4f){0.f, 0.f, 0.f, 0.f};
    int nt0 = wave * 2, nt1 = wave * 2 + 1;

#pragma unroll
    for (int kb = 0; kb < NB; kb++) {
        const float* tp = &T[row * TSTRIDE + kb * TC + ch0];
        v8s a;
#pragma unroll
        for (int q = 0; q < 8; q++) a[q] = f2bf(tp[q]);
        long b0 = ((long)((kb * 4 + pass) * 8 + nt0) * 64 + lane) * 8;
        long b1 = ((long)((kb * 4 + pass) * 8 + nt1) * 64 + lane) * 8;
        v8s bh0 = *(const v8s*)(Wh + b0);
        v8s bh1 = *(const v8s*)(Wh + b1);
        acc0 = __builtin_amdgcn_mfma_f32_16x16x32_bf16(a, bh0, acc0, 0, 0, 0);
        acc1 = __builtin_amdgcn_mfma_f32_16x16x32_bf16(a, bh1, acc1, 0, 0, 0);
    }

    // Epilogue. C/D layout: col = lane&15, row-in-tile = (lane>>4)*4 + r.
    int colr = lane & 15;
    int rbase = ((lane >> 4) & 3) * 4;
#pragma unroll
    for (int r = 0; r < 4; r++) {
        int n = n0 + rbase + r;
        size_t o0 = (size_t)n * HDIM + nt0 * 16 + colr;
        size_t o1 = (size_t)n * HDIM + nt1 * 16 + colr;
        if (pass == 0) {
            outp[o0] = acc0[r] + bias[nt0 * 16 + colr];
            outp[o1] = acc1[r] + bias[nt1 * 16 + colr];
        } else {
            outp[o0] += acc0[r];
            outp[o1] += acc1[r];
        }
    }
}

// ---------------------------------------------------------------------------
extern "C" void kernel_launch(void* const* d_in, const int* in_sizes, int n_in,
                              void* d_out, int out_size, void* d_ws, size_t ws_size,
                              hipStream_t stream) {
    const float* x   = (const float*)d_in[0];
    const void*  eix = d_in[1];
    const float* ea  = (const float*)d_in[2];
    const float* Wp1 = (const float*)d_in[3];
    const float* bp1 = (const float*)d_in[4];
    const float* Wp2 = (const float*)d_in[5];
    const float* bp2 = (const float*)d_in[6];
    const float* W[3]  = {(const float*)d_in[7],  (const float*)d_in[10], (const float*)d_in[13]};
    const float* Wr[3] = {(const float*)d_in[8],  (const float*)d_in[11], (const float*)d_in[14]};
    const float* b[3]  = {(const float*)d_in[9],  (const float*)d_in[12], (const float*)d_in[15]};
    float* out = (float*)d_out;

    char* ws = (char*)d_ws;
    size_t off = 0;
    auto walloc = [&](size_t bytes) -> void* {
        void* p = ws + off;
        off = (off + bytes + 255) & ~(size_t)255;
        return p;
    };
    int*   flag    = (int*)  walloc(sizeof(int));
    int*   e32     = (int*)  walloc(sizeof(int) * 2 * E_EDGES);
    ush*   wq      = (ush*)  walloc(sizeof(ush) * (size_t)NTAP);
    uch*   kq      = (uch*)  walloc((size_t)NTAP);
    float* h0      = (float*)walloc(sizeof(float) * (size_t)N_NODES * HDIM);
    float* h1      = (float*)walloc(sizeof(float) * (size_t)N_NODES * HDIM);
    ush*   xb      = (ush*)  walloc(sizeof(ush) * (size_t)N_NODES * CIN);
    short* Wh      = (short*)walloc(sizeof(short) * (size_t)NB * 128 * 128);
    int*   hist    = (int*)  walloc(sizeof(int) * BINS);
    int*   cursor  = (int*)  walloc(sizeof(int) * BINS);
    int*   rowptrT = (int*)  walloc(sizeof(int) * (BINS + 1));
    int*   bsum    = (int*)  walloc(sizeof(int) * 1024);
    int*   srcT    = (int*)  walloc(sizeof(int) * (size_t)NTAP);
    ush*   wT      = (ush*)  walloc(sizeof(ush) * (size_t)NTAP);

    int* srcv = e32;
    int* dstv = e32 + E_EDGES;

    detect_kernel<<<1, 1024, 0, stream>>>((const unsigned int*)eix, flag);
    decode_edges<<<(2 * E_EDGES + 255) / 256, 256, 0, stream>>>(eix, flag, e32, 2 * E_EDGES);
    edge_basis<<<(E_EDGES + 255) / 256, 256, 0, stream>>>(ea, Wp1, bp1, Wp2, bp2, wq, kq);

    // Tap-level CSR over (dst,k) bins; built once.
    const int nblkA = (BINS + 1023) / 1024;   // 528
    zero_int<<<(BINS + 255) / 256, 256, 0, stream>>>(hist, BINS);
    zero_int<<<(BINS + 255) / 256, 256, 0, stream>>>(cursor, BINS);
    histT_kernel<<<(NTAP + 255) / 256, 256, 0, stream>>>(dstv, kq, hist);
    scanA_kernel<<<nblkA, 256, 0, stream>>>(hist, rowptrT, bsum);
    scanB_kernel<<<1, 256, 0, stream>>>(bsum, nblkA);
    scanC_kernel<<<(BINS + 255) / 256, 256, 0, stream>>>(rowptrT, bsum);
    permT_kernel<<<(NTAP + 255) / 256, 256, 0, stream>>>(dstv, srcv, kq, wq,
                                                         rowptrT, cursor, srcT, wT);

    const float* lin[3]  = {x, h0, h1};
    float*       lout[3] = {h0, h1, out};

    for (int l = 0; l < 3; l++) {
        convX_kernel<<<(N_NODES * CIN + 255) / 256, 256, 0, stream>>>(
            lin[l], xb, (l > 0) ? 1 : 0);
        packW_kernel<<<(NB * 4 * 8 * 64 + 255) / 256, 256, 0, stream>>>(
            W[l], Wr[l], Wh);
        for (int p = 0; p < 4; p++) {
            fused_kernel<<<N_NODES / TN, 256, 0, stream>>>(
                xb, rowptrT, srcT, wT, Wh, b[l], lout[l], p);
        }
    }
}

// Round 13
// 626.441 us; speedup vs baseline: 9.0374x; 6.4601x over previous
//
#include <hip/hip_runtime.h>
#include <hip/hip_bf16.h>
#include <hip/hip_fp16.h>

#define N_NODES 20000
#define E_EDGES 320000
#define CIN 128
#define HDIM 128
#define EDGE_DIM 16
#define SDIM 3
#define KS 3
#define KK 27           // 3^3 kernel weight matrices
#define NB 28           // 27 spline blocks + 1 root-weight block
#define ZLD (NB * 128)  // Z leading dim = 3584 elements (bf16)
#define S_TAPS 8
#define MLP_HID 6
#define MT_TOTAL (N_NODES / 16)   // 1250 m-tiles of 16 rows

typedef __attribute__((ext_vector_type(8))) short v8s;   // 8 bf16 (4 VGPRs)
typedef __attribute__((ext_vector_type(4))) float v4f;   // MFMA accumulator
typedef unsigned short ush;
typedef unsigned char uch;

static __device__ __forceinline__ short f2bf(float v) {
    unsigned u = __float_as_uint(v);
    unsigned r = (u + 0x7fffu + ((u >> 16) & 1u)) >> 16;   // RTNE
    return (short)r;
}
static __device__ __forceinline__ float bf2f(unsigned s) {
    return __uint_as_float((s & 0xffffu) << 16);
}
static __device__ __forceinline__ float bf2f_lo(unsigned u) {
    return __uint_as_float(u << 16);
}
static __device__ __forceinline__ float bf2f_hi(unsigned u) {
    return __uint_as_float(u & 0xffff0000u);
}
static __device__ __forceinline__ unsigned short f2h(float f) {
    __half h = __float2half(f);
    return __half_as_ushort(h);
}
static __device__ __forceinline__ float h2f(unsigned u) {
    __half_raw r; r.x = (unsigned short)u;
    return __half2float(__half(r));
}

// ---------------------------------------------------------------------------
// edge_index dtype detect + decode (int64 vs int32 storage)
// ---------------------------------------------------------------------------
__global__ void detect_kernel(const unsigned int* __restrict__ e, int* __restrict__ flag) {
    __shared__ int s_nz;
    if (threadIdx.x == 0) s_nz = 0;
    __syncthreads();
    unsigned int v = e[threadIdx.x * 2 + 1];
    if (v != 0) atomicAdd(&s_nz, 1);
    __syncthreads();
    if (threadIdx.x == 0) *flag = (s_nz > 0) ? 1 : 0;
}

__global__ void decode_edges(const void* __restrict__ eraw, const int* __restrict__ flag,
                             int* __restrict__ e32, int n) {
    int i = blockIdx.x * blockDim.x + threadIdx.x;
    if (i >= n) return;
    if (*flag) e32[i] = ((const int*)eraw)[i];
    else       e32[i] = (int)(((const long long*)eraw)[i]);
}

// ---------------------------------------------------------------------------
// Edge MLP (16->6 relu ->3 sigmoid) + degree-1 open B-spline basis.
// Emits fp16 weights (wq[E][8]) and byte kernel indices (kq[E][8]).
// ---------------------------------------------------------------------------
__global__ void edge_basis(const float* __restrict__ ea,
                           const float* __restrict__ Wp1, const float* __restrict__ bp1,
                           const float* __restrict__ Wp2, const float* __restrict__ bp2,
                           ush* __restrict__ wq, uch* __restrict__ kq) {
    __shared__ float sW1[EDGE_DIM * MLP_HID];
    __shared__ float sb1[MLP_HID];
    __shared__ float sW2[MLP_HID * SDIM];
    __shared__ float sb2[SDIM];
    int t = threadIdx.x;
    if (t < EDGE_DIM * MLP_HID) sW1[t] = Wp1[t];
    if (t < MLP_HID)            sb1[t] = bp1[t];
    if (t < MLP_HID * SDIM)     sW2[t] = Wp2[t];
    if (t < SDIM)               sb2[t] = bp2[t];
    __syncthreads();
    int e = blockIdx.x * blockDim.x + t;
    if (e >= E_EDGES) return;

    float a[EDGE_DIM];
#pragma unroll
    for (int i = 0; i < EDGE_DIM; i++) a[i] = ea[(long)e * EDGE_DIM + i];

    float hid[MLP_HID];
#pragma unroll
    for (int j = 0; j < MLP_HID; j++) {
        float s = sb1[j];
#pragma unroll
        for (int i = 0; i < EDGE_DIM; i++) s += a[i] * sW1[i * MLP_HID + j];
        hid[j] = fmaxf(s, 0.f);
    }

    float lo[SDIM], fr[SDIM];
#pragma unroll
    for (int d = 0; d < SDIM; d++) {
        float s = sb2[d];
#pragma unroll
        for (int j = 0; j < MLP_HID; j++) s += hid[j] * sW2[j * SDIM + d];
        float u = 1.f / (1.f + expf(-s));
        float v = u * (float)(KS - 1);
        float l = floorf(v);
        l = fminf(fmaxf(l, 0.f), (float)(KS - 2));
        lo[d] = l;
        fr[d] = v - l;
    }

#pragma unroll
    for (int s = 0; s < S_TAPS; s++) {
        float w = 1.f;
        int idx = 0, stride = 1;
#pragma unroll
        for (int d = 0; d < SDIM; d++) {
            int bit = (s >> d) & 1;
            w *= bit ? fr[d] : (1.f - fr[d]);
            idx += ((int)lo[d] + bit) * stride;
            stride *= KS;
        }
        wq[(long)e * S_TAPS + s] = f2h(w);
        kq[(long)e * S_TAPS + s] = (uch)idx;
    }
}

// ---------------------------------------------------------------------------
// CSR build binned by (dst, src-chunk) — built once, reused for 3 layers
// ---------------------------------------------------------------------------
__global__ void zero_int(int* __restrict__ p, int n) {
    int i = blockIdx.x * blockDim.x + threadIdx.x;
    if (i < n) p[i] = 0;
}

__global__ void hist2_kernel(const int* __restrict__ dst, const int* __restrict__ src,
                             int* __restrict__ hist, int nc, int chunk_rows) {
    int e = blockIdx.x * blockDim.x + threadIdx.x;
    if (e >= E_EDGES) return;
    int bin = dst[e] * nc + src[e] / chunk_rows;
    atomicAdd(&hist[bin], 1);
}

__global__ void scan_kernel(const int* __restrict__ hist, int* __restrict__ rowptr, int B) {
    __shared__ int part[256];
    int t = threadIdx.x;
    const int per = (B + 255) / 256;
    int base = t * per;
    int s = 0;
    for (int i = 0; i < per; i++) {
        int idx = base + i;
        if (idx < B) s += hist[idx];
    }
    part[t] = s;
    __syncthreads();
    for (int off = 1; off < 256; off <<= 1) {
        int v = (t >= off) ? part[t - off] : 0;
        __syncthreads();
        part[t] += v;
        __syncthreads();
    }
    int run = (t == 0) ? 0 : part[t - 1];
    for (int i = 0; i < per; i++) {
        int idx = base + i;
        if (idx < B) { rowptr[idx] = run; run += hist[idx]; }
    }
    if (t == 255) rowptr[B] = run;
}

__global__ void perm2_kernel(const int* __restrict__ dst, const int* __restrict__ src,
                             const int* __restrict__ rowptr, int* __restrict__ cursor,
                             int* __restrict__ eperm, int nc, int chunk_rows) {
    int e = blockIdx.x * blockDim.x + threadIdx.x;
    if (e >= E_EDGES) return;
    int bin = dst[e] * nc + src[e] / chunk_rows;
    int pos = rowptr[bin] + atomicAdd(&cursor[bin], 1);
    eperm[pos] = e;
}

// Pack metadata into CSR order: sequential streaming in the gather.
__global__ void pack_csr(const int* __restrict__ eperm, const int* __restrict__ src,
                         const ush* __restrict__ wq, const uch* __restrict__ kq,
                         int* __restrict__ srcp, ush* __restrict__ wp, uch* __restrict__ kp) {
    int j = blockIdx.x * blockDim.x + threadIdx.x;
    if (j >= E_EDGES) return;
    int e = eperm[j];
    srcp[j] = src[e];
    *(uint4*)(wp + (size_t)j * 8) = *(const uint4*)(wq + (size_t)e * 8);
    *(uint2*)(kp + (size_t)j * 8) = *(const uint2*)(kq + (size_t)e * 8);
}

// ---------------------------------------------------------------------------
// Convert activations -> bf16 (RTNE) in MFMA A-fragment layout.
// Only needed for layer 0 (from x) and the nc>1 fallback path.
// ---------------------------------------------------------------------------
__global__ void convA_kernel(const float* __restrict__ A, short* __restrict__ hi,
                             int do_relu) {
    int gid = blockIdx.x * blockDim.x + threadIdx.x;
    if (gid >= MT_TOTAL * 4 * 64) return;
    int lane = gid & 63;
    int ks = (gid >> 6) & 3;
    int mt = gid >> 8;
    int row = mt * 16 + (lane & 15);
    int col = ks * 32 + ((lane >> 4) & 3) * 8;
    const float* p = A + (long)row * CIN + col;
    long off = ((long)(mt * 4 + ks) * 64 + lane) * 8;
#pragma unroll
    for (int j = 0; j < 8; j++) {
        float v = p[j];
        if (do_relu) v = fmaxf(v, 0.f);
        hi[off + j] = f2bf(v);
    }
}

// ---------------------------------------------------------------------------
// Pack [W (27 blocks) | Wr] of ALL 3 LAYERS -> bf16 MFMA B-fragment layout.
// One dispatch, reused across the layer loop.
// ---------------------------------------------------------------------------
__global__ void packW3_kernel(const float* __restrict__ W0, const float* __restrict__ Wr0,
                              const float* __restrict__ W1, const float* __restrict__ Wr1,
                              const float* __restrict__ W2, const float* __restrict__ Wr2,
                              short* __restrict__ hi) {
    int gid = blockIdx.x * blockDim.x + threadIdx.x;
    if (gid >= 3 * NB * 4 * 8 * 64) return;
    int lane = gid & 63;
    int nt = (gid >> 6) & 7;
    int ks = (gid >> 9) & 3;
    int kb2 = gid >> 11;           // 0..83
    int layer = kb2 / NB;
    int kb = kb2 - layer * NB;
    const float* W  = (layer == 0) ? W0  : (layer == 1) ? W1  : W2;
    const float* Wr = (layer == 0) ? Wr0 : (layer == 1) ? Wr1 : Wr2;
    int i0 = ks * 32 + ((lane >> 4) & 3) * 8;
    int o = nt * 16 + (lane & 15);
    const float* src = (kb < KK) ? (W + (long)kb * 16384 + (long)i0 * 128 + o)
                                 : (Wr + (long)i0 * 128 + o);
    long off = ((long)(((size_t)layer * NB + kb) * 4 + ks) * 8 + nt) * 64 * 8
             + (long)lane * 8;
#pragma unroll
    for (int j = 0; j < 8; j++) {
        float v = src[(long)j * 128];
        hi[off + j] = f2bf(v);
    }
}

// ---------------------------------------------------------------------------
// MFMA GEMM: Z[row-row_lo, kb*128+o] = sum_i A[row,i]*B[kb][i][o]  (bf16 out)
// Plain bf16 A and W. grid = (kb fast, m-group) for A locality.
// ---------------------------------------------------------------------------
__global__ __launch_bounds__(256) void gemm_kernel(
    const short* __restrict__ Ah, const short* __restrict__ Wh,
    ush* __restrict__ Z, int mtile_lo, int mtile_hi, int row_lo, int row_hi)
{
    int wave = threadIdx.x >> 6;
    int lane = threadIdx.x & 63;
    int kb = blockIdx.x;                               // fast-varying -> A locality
    int mt0 = mtile_lo + blockIdx.y * 8 + wave * 2;
    if (mt0 >= mtile_hi) return;
    int mt1 = (mt0 + 1 < mtile_hi) ? (mt0 + 1) : mt0;

    v4f acc[2][8];
#pragma unroll
    for (int m = 0; m < 2; m++)
#pragma unroll
        for (int n = 0; n < 8; n++) acc[m][n] = (v4f){0.f, 0.f, 0.f, 0.f};

#pragma unroll
    for (int ks = 0; ks < 4; ks++) {
        long a0 = ((long)(mt0 * 4 + ks) * 64 + lane) * 8;
        long a1 = ((long)(mt1 * 4 + ks) * 64 + lane) * 8;
        v8s ah0 = *(const v8s*)(Ah + a0);
        v8s ah1 = *(const v8s*)(Ah + a1);
#pragma unroll
        for (int nt = 0; nt < 8; nt++) {
            long boff = ((long)((kb * 4 + ks) * 8 + nt) * 64 + lane) * 8;
            v8s bh = *(const v8s*)(Wh + boff);
            acc[0][nt] = __builtin_amdgcn_mfma_f32_16x16x32_bf16(ah0, bh, acc[0][nt], 0, 0, 0);
            acc[1][nt] = __builtin_amdgcn_mfma_f32_16x16x32_bf16(ah1, bh, acc[1][nt], 0, 0, 0);
        }
    }

    // C/D layout: col = lane&15, row-in-tile = (lane>>4)*4 + reg
#pragma unroll
    for (int m = 0; m < 2; m++) {
        int mtg = mt0 + m;
        if (mtg >= mtile_hi) break;
#pragma unroll
        for (int nt = 0; nt < 8; nt++) {
            int col = kb * 128 + nt * 16 + (lane & 15);
#pragma unroll
            for (int r = 0; r < 4; r++) {
                int row = mtg * 16 + ((lane >> 4) & 3) * 4 + r;
                if (row >= row_hi) continue;
                Z[(size_t)(row - row_lo) * ZLD + col] = (ush)f2bf(acc[m][nt][r]);
            }
        }
    }
}

// ---------------------------------------------------------------------------
// Gather v5: one wave per dst node; tap pairs hit adjacent kernel blocks =>
// 4x512B contiguous reads per edge. Lane = (pair p) x (block-bit b) x
// (ch-chunk g, 16 ch). Tap reduction via shfl_xor 8/16/32; lanes 0-7 hold
// the 128-ch result and write it out.
//   mode 0: fp32 outp (+first-chunk RMW semantics) — R9-verified path.
//   mode 1: write bf16 MFMA A-fragment (next layer's Ah) with relu —
//           valid only when nc==1 (full sum available in one pass).
// ---------------------------------------------------------------------------
__global__ __launch_bounds__(256) void gather5_kernel(
    const ush* __restrict__ Z, const int* __restrict__ rowptr,
    const int* __restrict__ srcp, const ush* __restrict__ wp,
    const uch* __restrict__ kp, const float* __restrict__ bias,
    float* __restrict__ outp, short* __restrict__ Ahout,
    int lo, int hi, int nc, int cidx, int first, int mode)
{
    int wave = threadIdx.x >> 6;
    int lane = threadIdx.x & 63;
    int n = blockIdx.x * 4 + wave;
    int p = lane >> 4;             // tap pair 0..3
    int b = (lane >> 3) & 1;       // block within pair
    int g = lane & 7;              // channel chunk (16 ch)
    int cb = g * 16;

    int bin = n * nc + cidx;
    int jb = rowptr[bin], je = rowptr[bin + 1];

    float acc[16];
#pragma unroll
    for (int i = 0; i < 16; i++) acc[i] = 0.f;

#pragma unroll 4
    for (int j = jb; j < je; j++) {
        int s = srcp[j];
        int kbase = kp[(size_t)j * 8 + 2 * p];          // pair base block
        float w = h2f(wp[(size_t)j * 8 + 2 * p + b]);   // this block's weight
        const ush* zb = Z + (size_t)(s - lo) * ZLD + (kbase + b) * 128 + cb;
        uint4 z0 = *(const uint4*)(zb);       // ch cb+0 .. cb+7
        uint4 z1 = *(const uint4*)(zb + 8);   // ch cb+8 .. cb+15
        acc[0]  += w * bf2f_lo(z0.x);  acc[1]  += w * bf2f_hi(z0.x);
        acc[2]  += w * bf2f_lo(z0.y);  acc[3]  += w * bf2f_hi(z0.y);
        acc[4]  += w * bf2f_lo(z0.z);  acc[5]  += w * bf2f_hi(z0.z);
        acc[6]  += w * bf2f_lo(z0.w);  acc[7]  += w * bf2f_hi(z0.w);
        acc[8]  += w * bf2f_lo(z1.x);  acc[9]  += w * bf2f_hi(z1.x);
        acc[10] += w * bf2f_lo(z1.y);  acc[11] += w * bf2f_hi(z1.y);
        acc[12] += w * bf2f_lo(z1.z);  acc[13] += w * bf2f_hi(z1.z);
        acc[14] += w * bf2f_lo(z1.w);  acc[15] += w * bf2f_hi(z1.w);
    }

    // Reduce over the 8 (pair, block) contributors: lanes differing in bits 3,4,5.
#pragma unroll
    for (int m = 8; m <= 32; m <<= 1) {
#pragma unroll
        for (int i = 0; i < 16; i++) acc[i] += __shfl_xor(acc[i], m, 64);
    }

    if (lane < 8) {                // p==0, b==0 lanes hold the totals
        if (n >= lo && n < hi) {   // root weight + bias (chunk owning node n)
            const ush* zr = Z + (size_t)(n - lo) * ZLD + KK * 128 + cb;
            uint4 r0 = *(const uint4*)(zr);
            uint4 r1 = *(const uint4*)(zr + 8);
            const float4* bp4 = (const float4*)(bias + cb);
            float4 b0 = bp4[0], b1 = bp4[1], b2 = bp4[2], b3 = bp4[3];
            acc[0]  += bf2f_lo(r0.x) + b0.x;  acc[1]  += bf2f_hi(r0.x) + b0.y;
            acc[2]  += bf2f_lo(r0.y) + b0.z;  acc[3]  += bf2f_hi(r0.y) + b0.w;
            acc[4]  += bf2f_lo(r0.z) + b1.x;  acc[5]  += bf2f_hi(r0.z) + b1.y;
            acc[6]  += bf2f_lo(r0.w) + b1.z;  acc[7]  += bf2f_hi(r0.w) + b1.w;
            acc[8]  += bf2f_lo(r1.x) + b2.x;  acc[9]  += bf2f_hi(r1.x) + b2.y;
            acc[10] += bf2f_lo(r1.y) + b2.z;  acc[11] += bf2f_hi(r1.y) + b2.w;
            acc[12] += bf2f_lo(r1.z) + b3.x;  acc[13] += bf2f_hi(r1.z) + b3.y;
            acc[14] += bf2f_lo(r1.w) + b3.z;  acc[15] += bf2f_hi(r1.w) + b3.w;
        }
        if (mode == 1) {
            // relu + write next layer's Ah in MFMA A-fragment layout:
            // Ah[((mt*4+ks)*64 + (r + 16*sub))*8 + j] = A[n][ks*32+sub*8+j]
            int mt = n >> 4, r = n & 15;
            int ks = g >> 1;
            int sub0 = (g * 2) & 3;
            int sub1 = (g * 2 + 1) & 3;
            v8s p0, p1;
#pragma unroll
            for (int q = 0; q < 8; q++) {
                p0[q] = f2bf(fmaxf(acc[q], 0.f));
                p1[q] = f2bf(fmaxf(acc[8 + q], 0.f));
            }
            long base = (long)(mt * 4 + ks) * 64;
            *(v8s*)(Ahout + (base + r + 16 * sub0) * 8) = p0;
            *(v8s*)(Ahout + (base + r + 16 * sub1) * 8) = p1;
        } else {
            float* op = outp + (size_t)n * HDIM + cb;
            if (!first) {
                const float4* o4 = (const float4*)op;
#pragma unroll
                for (int q = 0; q < 4; q++) {
                    float4 ov = o4[q];
                    acc[q * 4 + 0] += ov.x; acc[q * 4 + 1] += ov.y;
                    acc[q * 4 + 2] += ov.z; acc[q * 4 + 3] += ov.w;
                }
            }
#pragma unroll
            for (int q = 0; q < 4; q++) {
                float4 ov = make_float4(acc[q * 4 + 0], acc[q * 4 + 1],
                                        acc[q * 4 + 2], acc[q * 4 + 3]);
                ((float4*)op)[q] = ov;
            }
        }
    }
}

// ---------------------------------------------------------------------------
extern "C" void kernel_launch(void* const* d_in, const int* in_sizes, int n_in,
                              void* d_out, int out_size, void* d_ws, size_t ws_size,
                              hipStream_t stream) {
    const float* x   = (const float*)d_in[0];
    const void*  eix = d_in[1];
    const float* ea  = (const float*)d_in[2];
    const float* Wp1 = (const float*)d_in[3];
    const float* bp1 = (const float*)d_in[4];
    const float* Wp2 = (const float*)d_in[5];
    const float* bp2 = (const float*)d_in[6];
    const float* W[3]  = {(const float*)d_in[7],  (const float*)d_in[10], (const float*)d_in[13]};
    const float* Wr[3] = {(const float*)d_in[8],  (const float*)d_in[11], (const float*)d_in[14]};
    const float* b[3]  = {(const float*)d_in[9],  (const float*)d_in[12], (const float*)d_in[15]};
    float* out = (float*)d_out;

    char* ws = (char*)d_ws;
    size_t off = 0;
    auto walloc = [&](size_t bytes) -> void* {
        void* p = ws + off;
        off = (off + bytes + 255) & ~(size_t)255;
        return p;
    };
    int*   flag    = (int*)  walloc(sizeof(int));
    int*   e32     = (int*)  walloc(sizeof(int) * 2 * E_EDGES);
    ush*   wq      = (ush*)  walloc(sizeof(ush) * (size_t)E_EDGES * 8);
    uch*   kq      = (uch*)  walloc((size_t)E_EDGES * 8);
    float* h0      = (float*)walloc(sizeof(float) * (size_t)N_NODES * HDIM);
    float* h1      = (float*)walloc(sizeof(float) * (size_t)N_NODES * HDIM);
    short* Ah      = (short*)walloc(sizeof(short) * (size_t)N_NODES * CIN);
    short* Wh3     = (short*)walloc(sizeof(short) * (size_t)3 * NB * 128 * 128);
    int*   eperm   = (int*)  walloc(sizeof(int) * E_EDGES);
    int*   srcp    = (int*)  walloc(sizeof(int) * E_EDGES);
    ush*   wp      = (ush*)  walloc(sizeof(ush) * (size_t)E_EDGES * 8);
    uch*   kp      = (uch*)  walloc((size_t)E_EDGES * 8);

    // Pick the smallest chunk count nc such that CSR arrays + Z fit (R9 logic).
    int  nc = -1;
    long chunk_rows = 0;
    for (int t = 1; t <= 157; t++) {
        long cr = (((N_NODES + t - 1) / t) + 127) / 128 * 128;
        size_t bins = (size_t)N_NODES * t;
        size_t need = 0;
        auto a = [&](size_t bb) { need += (bb + 255) & ~(size_t)255; };
        a(sizeof(int) * bins * 2);         // hist+cursor (one block)
        a(sizeof(int) * (bins + 1));       // rowptr
        a((size_t)cr * ZLD * sizeof(ush)); // Z
        if (off + need <= ws_size) { nc = t; chunk_rows = cr; break; }
    }
    if (nc < 0) { nc = 157; chunk_rows = 128; }
    size_t bins = (size_t)N_NODES * nc;
    int*   histcur = (int*)walloc(sizeof(int) * bins * 2);
    int*   hist    = histcur;
    int*   cursor  = histcur + bins;
    int*   rowptr  = (int*)walloc(sizeof(int) * (bins + 1));
    ush*   Z       = (ush*)walloc((size_t)chunk_rows * ZLD * sizeof(ush));

    int* srcv = e32;
    int* dstv = e32 + E_EDGES;
    const int fast = (nc == 1) ? 1 : 0;

    detect_kernel<<<1, 1024, 0, stream>>>((const unsigned int*)eix, flag);
    decode_edges<<<(2 * E_EDGES + 255) / 256, 256, 0, stream>>>(eix, flag, e32, 2 * E_EDGES);
    edge_basis<<<(E_EDGES + 255) / 256, 256, 0, stream>>>(ea, Wp1, bp1, Wp2, bp2, wq, kq);

    // CSR binned by (dst, src-chunk); built once, reused across 3 layers
    zero_int<<<((int)(bins * 2) + 255) / 256, 256, 0, stream>>>(histcur, (int)(bins * 2));
    hist2_kernel<<<(E_EDGES + 255) / 256, 256, 0, stream>>>(dstv, srcv, hist, nc, (int)chunk_rows);
    scan_kernel<<<1, 256, 0, stream>>>(hist, rowptr, (int)bins);
    perm2_kernel<<<(E_EDGES + 255) / 256, 256, 0, stream>>>(dstv, srcv, rowptr, cursor,
                                                            eperm, nc, (int)chunk_rows);
    pack_csr<<<(E_EDGES + 255) / 256, 256, 0, stream>>>(eperm, srcv, wq, kq, srcp, wp, kp);

    // All three layers' weights packed in one dispatch
    packW3_kernel<<<(3 * NB * 4 * 8 * 64 + 255) / 256, 256, 0, stream>>>(
        W[0], Wr[0], W[1], Wr[1], W[2], Wr[2], Wh3);

    const float* lin[3]  = {x, h0, h1};
    float*       lout[3] = {h0, h1, out};

    for (int l = 0; l < 3; l++) {
        // Ah source: layer 0 converts from x; in fast mode layers 1,2 already
        // have Ah written by the previous gather (bf16 + relu). Fallback
        // (nc>1) converts from the fp32 h arrays as in R9.
        if (l == 0) {
            convA_kernel<<<(MT_TOTAL * 4 * 64 + 255) / 256, 256, 0, stream>>>(
                x, Ah, 0);
        } else if (!fast) {
            convA_kernel<<<(MT_TOTAL * 4 * 64 + 255) / 256, 256, 0, stream>>>(
                lin[l], Ah, 1);
        }
        const short* Wh = Wh3 + (size_t)l * NB * 128 * 128;
        int mode = (fast && l < 2) ? 1 : 0;
        for (int c = 0; c < nc; c++) {
            long lo = (long)c * chunk_rows;
            long hi = lo + chunk_rows;
            if (hi > N_NODES) hi = N_NODES;
            if (lo >= N_NODES) break;
            int mtile_lo = (int)(lo / 16);
            int mtile_hi = (int)((hi + 15) / 16);
            int gy = (mtile_hi - mtile_lo + 7) / 8;
            dim3 grid(NB, gy);
            gemm_kernel<<<grid, 256, 0, stream>>>(Ah, Wh, Z,
                                                  mtile_lo, mtile_hi, (int)lo, (int)hi);
            gather5_kernel<<<N_NODES / 4, 256, 0, stream>>>(
                Z, rowptr, srcp, wp, kp, b[l], lout[l], Ah,
                (int)lo, (int)hi, nc, c, (c == 0) ? 1 : 0, mode);
        }
    }
}